// Round 5
// baseline (765.966 us; speedup 1.0000x reference)
//
#include <hip/hip_runtime.h>

#define BB 256
#define TT 1024
#define KK 64

// One block per batch item, 512 threads = 8 waves.
// Chains are SINGLE-WAVE, all-register: lane j owns state j; the all-to-all
// matvec/max uses v_readlane broadcasts (no LDS, no barriers, no waitcnt).
//   wave0: forward (exp-domain, renorm every 8 steps)  -- E in 16 named float4
//   wave1: Viterbi max-only + checkpoint every 32 steps -- C in 16 named float4
//   wave2: gold-path score
//   waves 3-7: park at the phase barrier
// Phase B (all 8 waves): recompute 32-step segments from checkpoints with the
// tie-exact argmax tournament (strict >, lower index wins), filling bpl.
//
// KEY LESSON from rounds 2-3: float E[64] + by-ref lambda captures defeated
// SROA -> arrays went to scratch -> 64 scratch reads per serial step
// (VGPR_Count=52 was the tell). Everything below is named variables with
// static accesses only: no lambdas, no arrays, no runtime indexing.
__device__ __forceinline__ float rlane(float x, int i) {
  return __int_as_float(__builtin_amdgcn_readlane(__float_as_int(x), i));
}

__device__ __forceinline__ float wavemax(float v) {
#pragma unroll
  for (int off = 1; off <= 32; off <<= 1) v = fmaxf(v, __shfl_xor(v, off));
  return v;
}

// ---- transition-column loads (lane j holds column j as 16 float4) ----
#define LDE(n) float4 E##n = make_float4( \
    __expf(trans[(4*(n)+0)*KK + j]), __expf(trans[(4*(n)+1)*KK + j]), \
    __expf(trans[(4*(n)+2)*KK + j]), __expf(trans[(4*(n)+3)*KK + j]));
#define LDC(n) float4 C##n = make_float4( \
    trans[(4*(n)+0)*KK + j], trans[(4*(n)+1)*KK + j], \
    trans[(4*(n)+2)*KK + j], trans[(4*(n)+3)*KK + j]);
#define LDD(n) float4 D##n = make_float4( \
    trans[(4*(n)+0)*KK + j], trans[(4*(n)+1)*KK + j], \
    trans[(4*(n)+2)*KK + j], trans[(4*(n)+3)*KK + j]);

// ---- forward: 4-way accumulated dot via readlane broadcast ----
#define FWD_Q(n, S) \
  q0 = __builtin_fmaf(rlane(S, 4*(n)+0), E##n.x, q0); \
  q1 = __builtin_fmaf(rlane(S, 4*(n)+1), E##n.y, q1); \
  q2 = __builtin_fmaf(rlane(S, 4*(n)+2), E##n.z, q2); \
  q3 = __builtin_fmaf(rlane(S, 4*(n)+3), E##n.w, q3);
#define FWD_QALL(S) \
  FWD_Q(0,S) FWD_Q(1,S) FWD_Q(2,S) FWD_Q(3,S) FWD_Q(4,S) FWD_Q(5,S) \
  FWD_Q(6,S) FWD_Q(7,S) FWD_Q(8,S) FWD_Q(9,S) FWD_Q(10,S) FWD_Q(11,S) \
  FWD_Q(12,S) FWD_Q(13,S) FWD_Q(14,S) FWD_Q(15,S)

#define FWD_STEP(T_, E_, M_) { \
  float q0 = 0.f, q1 = 0.f, q2 = 0.f, q3 = 0.f; \
  FWD_QALL(x) \
  float q = (q0 + q1) + (q2 + q3); \
  q *= (E_); \
  q = (M_) ? q : x; \
  if (((T_) & 7) == 0) {  /* renorm by max of PRE-update s (wave-uniform) */ \
    float gm = wavemax(x); \
    q *= __builtin_amdgcn_rcpf(gm); \
    offset += __logf(gm); \
  } \
  x = q; }

#define FWD_ITER(K_, EP_, MP_) { \
  int t = tb + (K_); \
  float e = EP_; int m = MP_; \
  int tpre = t + 4; if (tpre > TT - 1) tpre = TT - 1; \
  EP_ = __expf(emb[(size_t)tpre * KK + j]); \
  MP_ = mrow[tpre]; \
  FWD_STEP(t, e, m) }

// ---- viterbi max-only (fmax is exactly associative; tree shape free) ----
#define VIT_Q(n) float vm##n; { \
  float v0 = rlane(x, 4*(n)+0) + C##n.x; \
  float v1 = rlane(x, 4*(n)+1) + C##n.y; \
  float v2 = rlane(x, 4*(n)+2) + C##n.z; \
  float v3 = rlane(x, 4*(n)+3) + C##n.w; \
  vm##n = fmaxf(fmaxf(v0, v1), fmaxf(v2, v3)); }

#define VIT_STEP(T_, E_, M_) { \
  VIT_Q(0) VIT_Q(1) VIT_Q(2) VIT_Q(3) VIT_Q(4) VIT_Q(5) VIT_Q(6) VIT_Q(7) \
  VIT_Q(8) VIT_Q(9) VIT_Q(10) VIT_Q(11) VIT_Q(12) VIT_Q(13) VIT_Q(14) VIT_Q(15) \
  float b0 = fmaxf(vm0, vm1),   b1 = fmaxf(vm2, vm3); \
  float b2 = fmaxf(vm4, vm5),   b3 = fmaxf(vm6, vm7); \
  float b4 = fmaxf(vm8, vm9),   b5 = fmaxf(vm10, vm11); \
  float b6 = fmaxf(vm12, vm13), b7 = fmaxf(vm14, vm15); \
  float best = fmaxf(fmaxf(fmaxf(b0, b1), fmaxf(b2, b3)), \
                     fmaxf(fmaxf(b4, b5), fmaxf(b6, b7))); \
  float nd = (M_) ? (best + (E_)) : x; \
  if (((T_) & 31) == 0) ckpt[(T_) >> 5][j] = nd; \
  x = nd; }

#define VIT_ITER(K_, EP_, MP_) { \
  int t = tb + (K_); \
  float e = EP_; int m = MP_; \
  int tpre = t + 4; if (tpre > TT - 1) tpre = TT - 1; \
  EP_ = emb[(size_t)tpre * KK + j]; \
  MP_ = mrow[tpre]; \
  VIT_STEP(t, e, m) }

// ---- phase-B tie-exact argmax over one group of 8 (strict >, low idx wins) ----
#define ARG_G(na, nb, o) { \
  float v0 = rlane(x2, (o)+0) + D##na.x; \
  float v1 = rlane(x2, (o)+1) + D##na.y; \
  float v2 = rlane(x2, (o)+2) + D##na.z; \
  float v3 = rlane(x2, (o)+3) + D##na.w; \
  float v4 = rlane(x2, (o)+4) + D##nb.x; \
  float v5 = rlane(x2, (o)+5) + D##nb.y; \
  float v6 = rlane(x2, (o)+6) + D##nb.z; \
  float v7 = rlane(x2, (o)+7) + D##nb.w; \
  bool c0 = v1 > v0; float a0 = c0 ? v1 : v0; int i0 = c0 ? (o)+1 : (o)+0; \
  bool c1 = v3 > v2; float a1 = c1 ? v3 : v2; int i1 = c1 ? (o)+3 : (o)+2; \
  bool c2 = v5 > v4; float a2 = c2 ? v5 : v4; int i2 = c2 ? (o)+5 : (o)+4; \
  bool c3 = v7 > v6; float a3 = c3 ? v7 : v6; int i3 = c3 ? (o)+7 : (o)+6; \
  bool d0 = a1 > a0; float b0 = d0 ? a1 : a0; int k0 = d0 ? i1 : i0; \
  bool d1 = a3 > a2; float b1 = d1 ? a3 : a2; int k1 = d1 ? i3 : i2; \
  bool f0 = b1 > b0; float gv = f0 ? b1 : b0; int gi = f0 ? k1 : k0; \
  bool tk = gv > bv; bv = tk ? gv : bv; bi = tk ? gi : bi; }

__global__ __launch_bounds__(512)
__attribute__((amdgpu_waves_per_eu(1, 2)))
void crf_mega_kernel(
    const float* __restrict__ em, const int* __restrict__ mask,
    const float* __restrict__ trans, const int* __restrict__ tags,
    float* __restrict__ out_dec, float* ll_sum, int* match, int* maskSum) {

  __shared__ __align__(16) float ckpt[33][KK];  // delta checkpoints (+final in [32])
  __shared__ unsigned char mrow[TT];
  __shared__ unsigned char bpl[TT][KK];         // backpointers (64 KB)
  __shared__ unsigned char segm[32][KK];
  __shared__ unsigned char bs[40];
  __shared__ int redm[32];

  const int b = blockIdx.x;
  const int tid = threadIdx.x;
  const int wv = tid >> 6;
  const int j = tid & 63;

  const float* emb = em + (size_t)b * TT * KK;
  const int* mb = mask + (size_t)b * TT;
  const int* tgb = tags + (size_t)b * TT;

  for (int t = tid; t < TT; t += 512) mrow[t] = (unsigned char)(mb[t] ? 1 : 0);
  __syncthreads();  // B0

  if (wv == 0) {
    // =========================== FORWARD (wave 0) ===========================
    LDE(0) LDE(1) LDE(2) LDE(3) LDE(4) LDE(5) LDE(6) LDE(7)
    LDE(8) LDE(9) LDE(10) LDE(11) LDE(12) LDE(13) LDE(14) LDE(15)
    float raw = emb[j];
    float x, offset;
    {  // ---- t = 1 special: exponentiate raw e0 with global max ----
      float m0 = wavemax(raw);
      offset = m0;
      float s = __expf(raw - m0);
      float q0 = 0.f, q1 = 0.f, q2 = 0.f, q3 = 0.f;
      FWD_QALL(s)
      float q = (q0 + q1) + (q2 + q3);
      q *= __expf(emb[KK + j]);
      x = mrow[1] ? q : s;
    }
    float ep0 = __expf(emb[(size_t)2 * KK + j]);
    float ep1 = __expf(emb[(size_t)3 * KK + j]);
    float ep2 = __expf(emb[(size_t)4 * KK + j]);
    float ep3 = __expf(emb[(size_t)5 * KK + j]);
    int mp0 = mrow[2], mp1 = mrow[3], mp2 = mrow[4], mp3 = mrow[5];

    for (int tb = 2; tb + 3 <= TT - 1; tb += 4) {
      FWD_ITER(0, ep0, mp0)
      FWD_ITER(1, ep1, mp1)
      FWD_ITER(2, ep2, mp2)
      FWD_ITER(3, ep3, mp3)
    }
    // tail: t = 1022 (slot 0), t = 1023 (slot 1) -- static slot references
    FWD_STEP(TT - 2, ep0, mp0)
    FWD_STEP(TT - 1, ep1, mp1)

    float ssum = x;
#pragma unroll
    for (int off = 1; off <= 32; off <<= 1) ssum += __shfl_xor(ssum, off);
    if (tid == 0) atomicAdd(ll_sum, -(offset + __logf(ssum)));

  } else if (wv == 1) {
    // ====================== VITERBI max-only (wave 1) ======================
    LDC(0) LDC(1) LDC(2) LDC(3) LDC(4) LDC(5) LDC(6) LDC(7)
    LDC(8) LDC(9) LDC(10) LDC(11) LDC(12) LDC(13) LDC(14) LDC(15)
    float x = emb[j];
    ckpt[0][j] = x;
    float ep0 = emb[(size_t)1 * KK + j];
    float ep1 = emb[(size_t)2 * KK + j];
    float ep2 = emb[(size_t)3 * KK + j];
    float ep3 = emb[(size_t)4 * KK + j];
    int mp0 = mrow[1], mp1 = mrow[2], mp2 = mrow[3], mp3 = mrow[4];

    for (int tb = 1; tb + 3 <= TT - 1; tb += 4) {
      VIT_ITER(0, ep0, mp0)
      VIT_ITER(1, ep1, mp1)
      VIT_ITER(2, ep2, mp2)
      VIT_ITER(3, ep3, mp3)
    }
    // tail: t = 1021,1022,1023 -> slots 0,1,2
    VIT_STEP(TT - 3, ep0, mp0)
    VIT_STEP(TT - 2, ep1, mp1)
    VIT_STEP(TT - 1, ep2, mp2)

    ckpt[32][j] = x;   // final delta for last-tag argmax

  } else if (wv == 2) {
    // ========================= PATH SCORE (wave 2) =========================
    float acc = 0.f;
    int cnt = 0;
    for (int t = j; t < TT; t += 64) {
      if (mb[t]) {
        int tg = tgb[t];
        acc += emb[(size_t)t * KK + tg];
        cnt += 1;
        if (t >= 1) acc += trans[tgb[t - 1] * KK + tg];
      }
    }
#pragma unroll
    for (int off = 1; off <= 32; off <<= 1) {
      acc += __shfl_xor(acc, off);
      cnt += __shfl_xor(cnt, off);
    }
    if (j == 0) { atomicAdd(ll_sum, acc); atomicAdd(maskSum, cnt); }
  }
  // waves 3-7 fall through.

  __syncthreads();  // B1 — phase boundary

  // D loaded AFTER B1 so its registers never overlap the chain loops.
  LDD(0) LDD(1) LDD(2) LDD(3) LDD(4) LDD(5) LDD(6) LDD(7)
  LDD(8) LDD(9) LDD(10) LDD(11) LDD(12) LDD(13) LDD(14) LDD(15)

  // ====== PHASE B: per-segment argmax recompute (8 waves x 4 segments) ======
#pragma unroll 1
  for (int kk = 0; kk < 4; ++kk) {
    int s = wv + 8 * kk;
    int tS = 32 * s + 1;
    int tE = (s == 31) ? (TT - 1) : (32 * s + 32);
    float x2 = ckpt[s][j];
    float e_nx = emb[(size_t)tS * KK + j];
#pragma unroll 1
    for (int t = tS; t <= tE; ++t) {
      float e = e_nx;
      if (t < tE) e_nx = emb[(size_t)(t + 1) * KK + j];
      float bv = -__builtin_inff(); int bi = 0;
      ARG_G(0, 1, 0)   ARG_G(2, 3, 8)   ARG_G(4, 5, 16)  ARG_G(6, 7, 24)
      ARG_G(8, 9, 32)  ARG_G(10, 11, 40) ARG_G(12, 13, 48) ARG_G(14, 15, 56)
      int m = mrow[t];
      float nd = m ? (bv + e) : x2;
      int bp = m ? bi : j;
      bpl[t][j] = (unsigned char)bp;
      x2 = nd;
    }
  }
  __syncthreads();  // B2

  // ---- compose 32-step segment maps (4 chains per thread, ILP) ----
  {
    int j0 = tid & 63;
    int s0 = tid >> 6;     // 0..7
    int xs[4]; int tS[4], tE[4];
#pragma unroll
    for (int kk = 0; kk < 4; ++kk) {
      int s = s0 + 8 * kk;
      xs[kk] = j0;
      tS[kk] = 32 * s + 1;
      tE[kk] = (s == 31) ? (TT - 1) : (32 * s + 32);
    }
    for (int q = 0; q < 32; ++q) {
#pragma unroll
      for (int kk = 0; kk < 4; ++kk) {
        int t = tE[kk] - q;
        if (t >= tS[kk]) xs[kk] = bpl[t][xs[kk]];
      }
    }
#pragma unroll
    for (int kk = 0; kk < 4; ++kk) segm[s0 + 8 * kk][j0] = (unsigned char)xs[kk];
  }
  __syncthreads();  // B3

  if (tid == 0) {   // last_tag argmax (strict >, first max) + boundary walk
    float bd = ckpt[32][0];
    int lt = 0;
    for (int i = 1; i < KK; ++i) {
      float v2 = ckpt[32][i];
      if (v2 > bd) { bd = v2; lt = i; }
    }
    bs[32] = (unsigned char)lt;
    for (int s = 31; s >= 0; --s) bs[s] = segm[s][bs[s + 1]];
  }
  __syncthreads();  // B4

  if (tid < 32) {   // per-segment backtrace
    int s = tid;
    int x = bs[s + 1];
    int cnt = 0;
    int tEnd = (s == 31) ? (TT - 1) : (32 * s + 32);
    if (s == 31) {
      int m = mrow[TT - 1];
      out_dec[(size_t)b * TT + TT - 1] = (float)(m ? x : 0);
      cnt += (m && x == tgb[TT - 1]);
    }
    for (int t = tEnd; t >= 32 * s + 1; --t) {
      x = bpl[t][x];
      int m2 = mrow[t - 1];
      out_dec[(size_t)b * TT + t - 1] = (float)(m2 ? x : 0);
      cnt += (m2 && x == tgb[t - 1]);
    }
    redm[s] = cnt;
  }
  __syncthreads();  // B5
  if (tid == 0) {
    int c = 0;
    for (int s = 0; s < 32; ++s) c += redm[s];
    atomicAdd(match, c);
  }
}

__global__ void finalize_kernel(const float* ll_sum, const int* match,
                                const int* maskSum, float* d_out) {
  d_out[0] = -(*ll_sum) / (float)BB;
  d_out[1 + BB * TT] = (float)(*match) / (float)(*maskSum);
}

extern "C" void kernel_launch(void* const* d_in, const int* in_sizes, int n_in,
                              void* d_out, int out_size, void* d_ws, size_t ws_size,
                              hipStream_t stream) {
  const float* em = (const float*)d_in[0];
  const int* tags = (const int*)d_in[1];
  const int* mask = (const int*)d_in[2];       // bool -> int32 on device
  const float* trans = (const float*)d_in[3];
  float* out = (float*)d_out;

  float* ll_sum = (float*)d_ws;
  int* match = (int*)((char*)d_ws + 4);
  int* maskSum = (int*)((char*)d_ws + 8);

  hipMemsetAsync(d_ws, 0, 12, stream);
  crf_mega_kernel<<<BB, 512, 0, stream>>>(em, mask, trans, tags, out + 1,
                                          ll_sum, match, maskSum);
  finalize_kernel<<<1, 1, 0, stream>>>(ll_sum, match, maskSum, out);
}